// Round 4
// baseline (167.054 us; speedup 1.0000x reference)
//
#include <hip/hip_runtime.h>

typedef _Float16 half8_t __attribute__((ext_vector_type(8)));
typedef _Float16 half4_t __attribute__((ext_vector_type(4)));
typedef float    float4_t __attribute__((ext_vector_type(4)));

// ---------------- ws layout ----------------
// [0, 55296)        WqkvT  f16  [288][96]   WqkvT[f][k] = W_qkv[k][f]
// [55296, 73728)    WoutT  f16  [96][96]    WoutT[f][k] = W_out[k][f]
// [73728, 77824)    biasT  f32  [4][16][16] biasT[m][j][i] = bias_variant_m[i][j]
#define WOUTT_OFF_H 27648   // in f16 elements
#define BIAST_OFF_B 73728   // bytes

__global__ void prep_kernel(const float* __restrict__ Wqkv,
                            const float* __restrict__ Wout,
                            const float* __restrict__ pos,
                            _Float16* __restrict__ wqkvT,
                            _Float16* __restrict__ woutT,
                            float* __restrict__ biasT) {
  int idx = blockIdx.x * 256 + threadIdx.x;
  if (idx < 288 * 96) {
    int f = idx / 96, k = idx % 96;
    wqkvT[idx] = (_Float16)Wqkv[k * 288 + f];
  } else if (idx < 288 * 96 + 96 * 96) {
    int t = idx - 288 * 96;
    int f = t / 96, k = t % 96;
    woutT[t] = (_Float16)Wout[k * 96 + f];
  } else if (idx < 288 * 96 + 96 * 96 + 1024) {
    int t = idx - (288 * 96 + 96 * 96);
    int m = t >> 8, j = (t >> 4) & 15, i = t & 15;   // store [j][i] = bias[i][j]
    int xi = i >> 2, yi = i & 3, xj = j >> 2, yj = j & 3;
    // bias[i][j] = pos[idx[j] - idx[i] + 3]  (key minus query)
    float v = pos[(xj - xi + 3) * 7 + (yj - yi + 3)];
    if ((m & 1) && ((i >= 8) != (j >= 8))) v -= 1e9f;      // ul mask (last window row)
    if ((m & 2) && ((yi >= 2) != (yj >= 2))) v -= 1e9f;    // lr mask (last window col)
    biasT[t] = v;
  }
}

// ---------------- per-window LDS layout (f16 elements) ----------------
// QK: [16 tok][200]  feats 0..191 (q:0..95, k:96..191); after attn head h,
//     the PV output feats h*32..h*32+31 overwrite the (dead) q slots.
// VT: [96 vfeat][20] tokens 0..15
#define W_LDS 5120
#define QK_STRIDE 200
#define VT_STRIDE 20
#define VT_OFF 3200

// Fully wave-independent: 1 wave = 1 window, no __syncthreads. Within-wave
// LDS write->read ordering via explicit s_waitcnt lgkmcnt(0) ("memory" asm;
// dependents are ds_reads, i.e. memory ops, so the clobber orders them).
__global__ __launch_bounds__(256, 4)
void swin_fused(const float* __restrict__ x,
                const _Float16* __restrict__ wqkvT,
                const _Float16* __restrict__ woutT,
                const float* __restrict__ biasT,
                const float* __restrict__ b_out,
                float* __restrict__ out) {
  __shared__ _Float16 lds[4 * W_LDS];
  const int tid  = threadIdx.x;
  const int wave = tid >> 6;
  const int lane = tid & 63;
  const int l15  = lane & 15;
  const int g    = (lane >> 4) & 3;
  const int ty = l15 >> 2, tx = l15 & 3;

  const int blk   = blockIdx.x;
  const int batch = blk / 196;
  const int wid   = (blk % 196) * 4 + wave;   // this wave's window
  const int wrow = wid / 28, wcol = wid % 28;

  // token position with cyclic shift folded in (same addr used for the store)
  int p = wrow * 4 + ty + 2; if (p >= 112) p -= 112;
  int q = wcol * 4 + tx + 2; if (q >= 112) q -= 112;
  const float* xr = x + (((size_t)batch * 112 + p) * 112 + q) * 96 + g * 8;

  // ---- batch-issue all global x loads (one latency wait per wave)
  float4_t xa[3], xb[3];
#pragma unroll
  for (int kt = 0; kt < 3; ++kt) {
    xa[kt] = *(const float4_t*)(xr + kt * 32);
    xb[kt] = *(const float4_t*)(xr + kt * 32 + 4);
  }
  // bias loads issued early too (used only in attn)
  const int var = (wrow == 27 ? 1 : 0) + (wcol == 27 ? 2 : 0);
  const float* bt = biasT + var * 256 + g * 64 + l15;   // [var][j=4g+i'][i=l15]
  const float b0 = bt[0], b1 = bt[16], b2 = bt[32], b3 = bt[48];

  half8_t xf[3];
#pragma unroll
  for (int kt = 0; kt < 3; ++kt) {
    half8_t h;
    h[0] = (_Float16)xa[kt][0]; h[1] = (_Float16)xa[kt][1];
    h[2] = (_Float16)xa[kt][2]; h[3] = (_Float16)xa[kt][3];
    h[4] = (_Float16)xb[kt][0]; h[5] = (_Float16)xb[kt][1];
    h[6] = (_Float16)xb[kt][2]; h[7] = (_Float16)xb[kt][3];
    xf[kt] = h;
  }

  _Float16* qk = &lds[wave * W_LDS];
  _Float16* vt = &lds[wave * W_LDS + VT_OFF];

  // ---- GEMM1: this wave computes q,k,v for its own window (18 feature tiles)
#pragma unroll
  for (int f = 0; f < 18; ++f) {
    const _Float16* wp = &wqkvT[(f * 16 + l15) * 96 + g * 8];
    half8_t w0 = *(const half8_t*)(wp);
    half8_t w1 = *(const half8_t*)(wp + 32);
    half8_t w2 = *(const half8_t*)(wp + 64);
    float4_t acc = {0.f, 0.f, 0.f, 0.f};
    half4_t hh;
    if (f < 12) {
      // D = WqkvT_slice @ x^T : row = feat f*16+4g+i, col = tok l15
      acc = __builtin_amdgcn_mfma_f32_16x16x32_f16(w0, xf[0], acc, 0, 0, 0);
      acc = __builtin_amdgcn_mfma_f32_16x16x32_f16(w1, xf[1], acc, 0, 0, 0);
      acc = __builtin_amdgcn_mfma_f32_16x16x32_f16(w2, xf[2], acc, 0, 0, 0);
      hh[0] = (_Float16)acc[0]; hh[1] = (_Float16)acc[1];
      hh[2] = (_Float16)acc[2]; hh[3] = (_Float16)acc[3];
      *(half4_t*)&qk[l15 * QK_STRIDE + f * 16 + g * 4] = hh;
    } else {
      // D = x @ W_slice : row = tok 4g+i, col = feat -> vT[vfeat][tok]
      acc = __builtin_amdgcn_mfma_f32_16x16x32_f16(xf[0], w0, acc, 0, 0, 0);
      acc = __builtin_amdgcn_mfma_f32_16x16x32_f16(xf[1], w1, acc, 0, 0, 0);
      acc = __builtin_amdgcn_mfma_f32_16x16x32_f16(xf[2], w2, acc, 0, 0, 0);
      hh[0] = (_Float16)acc[0]; hh[1] = (_Float16)acc[1];
      hh[2] = (_Float16)acc[2]; hh[3] = (_Float16)acc[3];
      *(half4_t*)&vt[((f - 12) * 16 + l15) * VT_STRIDE + g * 4] = hh;
    }
  }
  // within-wave LDS writes -> reads: drain the DS queue (no cross-wave dep)
  asm volatile("s_waitcnt lgkmcnt(0)" ::: "memory");

  // ---- attention (all same-wave)
#pragma unroll
  for (int h = 0; h < 3; ++h) {
    // dots^T = K @ Q^T  (one 16x16x32 mfma; K = head_dim = 32)
    half8_t ak = *(const half8_t*)&qk[l15 * QK_STRIDE + 96 + h * 32 + g * 8];
    half8_t bq = *(const half8_t*)&qk[l15 * QK_STRIDE +      h * 32 + g * 8];
    float4_t dd = {0.f, 0.f, 0.f, 0.f};
    dd = __builtin_amdgcn_mfma_f32_16x16x32_f16(ak, bq, dd, 0, 0, 0);
    const float scale = 0.17677669529663687f;  // 32^-0.5
    float dv0 = dd[0] * scale + b0;
    float dv1 = dd[1] * scale + b1;
    float dv2 = dd[2] * scale + b2;
    float dv3 = dd[3] * scale + b3;
    // softmax over keys j (4 regs + lane-groups): col i fixed per lane
    float mx = fmaxf(fmaxf(dv0, dv1), fmaxf(dv2, dv3));
    mx = fmaxf(mx, __shfl_xor(mx, 16, 64));
    mx = fmaxf(mx, __shfl_xor(mx, 32, 64));
    float p0 = __expf(dv0 - mx), p1 = __expf(dv1 - mx);
    float p2 = __expf(dv2 - mx), p3 = __expf(dv3 - mx);
    float s = p0 + p1 + p2 + p3;
    s += __shfl_xor(s, 16, 64);
    s += __shfl_xor(s, 32, 64);
    float r = 1.0f / s;
    half4_t pb;   // P^T in D-layout == valid B-operand of 16x16x16 mfma
    pb[0] = (_Float16)(p0 * r); pb[1] = (_Float16)(p1 * r);
    pb[2] = (_Float16)(p2 * r); pb[3] = (_Float16)(p3 * r);
#pragma unroll
    for (int db = 0; db < 2; ++db) {
      // out^T[dblock] = v^T[dblock] @ P^T   (16x16, K=16 tokens)
      half4_t av = *(const half4_t*)&vt[(h * 32 + db * 16 + l15) * VT_STRIDE + g * 4];
      float4_t o = {0.f, 0.f, 0.f, 0.f};
      o = __builtin_amdgcn_mfma_f32_16x16x16f16(av, pb, o, 0, 0, 0);
      half4_t oh;
      oh[0] = (_Float16)o[0]; oh[1] = (_Float16)o[1];
      oh[2] = (_Float16)o[2]; oh[3] = (_Float16)o[3];
      // overwrite the (now dead) q slots of head h with attn output feats
      *(half4_t*)&qk[l15 * QK_STRIDE + h * 32 + db * 16 + g * 4] = oh;
    }
  }
  // PV ds_writes -> GEMM3 ds_reads (same wave)
  asm volatile("s_waitcnt lgkmcnt(0)" ::: "memory");

  // ---- GEMM3: y = WoutT @ out^T + b, store with inverse roll folded in
  {
    half8_t bf0 = *(const half8_t*)&qk[l15 * QK_STRIDE +      g * 8];
    half8_t bf1 = *(const half8_t*)&qk[l15 * QK_STRIDE + 32 + g * 8];
    half8_t bf2 = *(const half8_t*)&qk[l15 * QK_STRIDE + 64 + g * 8];
    float* orow = out + (((size_t)batch * 112 + p) * 112 + q) * 96;
#pragma unroll
    for (int mt = 0; mt < 6; ++mt) {
      const _Float16* wo = &woutT[(mt * 16 + l15) * 96 + g * 8];
      half8_t w0 = *(const half8_t*)(wo);
      half8_t w1 = *(const half8_t*)(wo + 32);
      half8_t w2 = *(const half8_t*)(wo + 64);
      float4_t acc = {0.f, 0.f, 0.f, 0.f};
      acc = __builtin_amdgcn_mfma_f32_16x16x32_f16(w0, bf0, acc, 0, 0, 0);
      acc = __builtin_amdgcn_mfma_f32_16x16x32_f16(w1, bf1, acc, 0, 0, 0);
      acc = __builtin_amdgcn_mfma_f32_16x16x32_f16(w2, bf2, acc, 0, 0, 0);
      float4_t bb = *(const float4_t*)&b_out[mt * 16 + g * 4];
      acc[0] += bb[0]; acc[1] += bb[1]; acc[2] += bb[2]; acc[3] += bb[3];
      *(float4_t*)&orow[mt * 16 + g * 4] = acc;
    }
  }
}

extern "C" void kernel_launch(void* const* d_in, const int* in_sizes, int n_in,
                              void* d_out, int out_size, void* d_ws, size_t ws_size,
                              hipStream_t stream) {
  const float* x    = (const float*)d_in[0];
  const float* Wqkv = (const float*)d_in[1];
  const float* pos  = (const float*)d_in[2];
  const float* Wout = (const float*)d_in[3];
  const float* bout = (const float*)d_in[4];
  char* ws = (char*)d_ws;
  _Float16* wqkvT = (_Float16*)ws;
  _Float16* woutT = ((_Float16*)ws) + WOUTT_OFF_H;
  float* biasT = (float*)(ws + BIAST_OFF_B);

  prep_kernel<<<148, 256, 0, stream>>>(Wqkv, Wout, pos, wqkvT, woutT, biasT);
  swin_fused<<<6272, 256, 0, stream>>>(x, wqkvT, woutT, biasT, bout, (float*)d_out);
}